// Round 6
// baseline (298.794 us; speedup 1.0000x reference)
//
#include <hip/hip_runtime.h>

#define D 64
#define OVF_CAP 65536

// ===========================================================================
// ws layout (256B aligned):
//   cnt    : N int          — per-row degree counter (memset 0 each call)
//   ovfCnt : 1 int          — overflow edge count    (memset 0 each call)
//   ovf    : OVF_CAP int4   — overflow edges (r, c, val_bits, _)
//   fb     : N*D ushort     — bf16 copy of features
//   pairs  : N*SLOTS int2   — (col, val_bits) for row r at pairs[r*SLOTS+k]
// ===========================================================================

__device__ inline unsigned short f32_to_bf16_rne(float x) {
    unsigned u = __float_as_uint(x);
    unsigned r = (u + 0x7FFFu + ((u >> 16) & 1u)) >> 16;
    return (unsigned short)r;
}

// ---- features f32 -> bf16 (vectorized) ----
__global__ void f2bf_kernel(const float4* __restrict__ in,
                            ushort4* __restrict__ out, int n4) {
    int i = blockIdx.x * blockDim.x + threadIdx.x;
    int stride = gridDim.x * blockDim.x;
    for (; i < n4; i += stride) {
        float4 f = in[i];
        ushort4 u;
        u.x = f32_to_bf16_rne(f.x);
        u.y = f32_to_bf16_rne(f.y);
        u.z = f32_to_bf16_rne(f.z);
        u.w = f32_to_bf16_rne(f.w);
        out[i] = u;
    }
}

// ---- slot scatter: NSLICE row-slices (XCD locality), 4-way unrolled ----
template <int SLOTS, int NSLICE>
__global__ void scatter_slot_kernel(const int* __restrict__ erows,
                                    const int* __restrict__ ecols,
                                    const float* __restrict__ evals,
                                    int* __restrict__ cnt,
                                    int2* __restrict__ pairs,
                                    int4* __restrict__ ovf,
                                    int* __restrict__ ovfCnt,
                                    int n_edges, int rows_per_slice) {
    const int slice = blockIdx.x & (NSLICE - 1);
    const int rlo   = slice * rows_per_slice;
    const int rhi   = rlo + rows_per_slice;
    const int sub   = blockIdx.x / NSLICE;
    const int t     = sub * blockDim.x + threadIdx.x;
    const int strid = (gridDim.x / NSLICE) * blockDim.x;

    auto handle = [&](int r, int c, float v) {
        if (r >= rlo && r < rhi) {
            int pos = atomicAdd(&cnt[r], 1);
            if (pos < SLOTS) {
                pairs[(size_t)r * SLOTS + pos] = make_int2(c, __float_as_int(v));
            } else {
                int oi = atomicAdd(ovfCnt, 1);
                if (oi < OVF_CAP) ovf[oi] = make_int4(r, c, __float_as_int(v), 0);
            }
        }
    };

    int e = t;
    for (; e + 3 * strid < n_edges; e += 4 * strid) {
        int e0 = e, e1 = e + strid, e2 = e + 2 * strid, e3 = e + 3 * strid;
        int   r0 = erows[e0], r1 = erows[e1], r2 = erows[e2], r3 = erows[e3];
        int   c0 = ecols[e0], c1 = ecols[e1], c2 = ecols[e2], c3 = ecols[e3];
        float v0 = evals[e0], v1 = evals[e1], v2 = evals[e2], v3 = evals[e3];
        handle(r0, c0, v0);
        handle(r1, c1, v1);
        handle(r2, c2, v2);
        handle(r3, c3, v3);
    }
    for (; e < n_edges; e += strid)
        handle(erows[e], ecols[e], evals[e]);
}

// ---- fused gather(bf16) + aggregate + project + relu. One wave per row,
//      grid-stride rows, sW staged once per block, shfl-broadcast proj. ----
template <int SLOTS>
__global__ void __launch_bounds__(256)
fused_slot_bf16(const unsigned short* __restrict__ fb,
                const int* __restrict__ cnt, const int2* __restrict__ pairs,
                const float* __restrict__ W, const int* __restrict__ ovfCnt,
                float* __restrict__ out, int n_rows) {
    __shared__ float sW[D * D];   // 16 KB
    for (int i = threadIdx.x; i < D * D; i += 256) sW[i] = W[i];
    __syncthreads();

    const int  w      = threadIdx.x >> 6;
    const int  lane   = threadIdx.x & 63;
    const bool doRelu = (*ovfCnt == 0);

    for (int row = blockIdx.x * 4 + w; row < n_rows; row += gridDim.x * 4) {
        int m = min(cnt[row], SLOTS);
        int px = 0, py = 0;
        if (lane < m) {                         // only filled slots touched
            int2 p = pairs[(size_t)row * SLOTS + lane];
            px = p.x; py = p.y;
        }
        float acc = 0.0f;
        int k = 0;
        for (; k + 4 <= m; k += 4) {
            int c0 = __shfl(px, k + 0), b0 = __shfl(py, k + 0);
            int c1 = __shfl(px, k + 1), b1 = __shfl(py, k + 1);
            int c2 = __shfl(px, k + 2), b2 = __shfl(py, k + 2);
            int c3 = __shfl(px, k + 3), b3 = __shfl(py, k + 3);
            float f0 = __uint_as_float((unsigned)fb[(size_t)c0 * D + lane] << 16);
            float f1 = __uint_as_float((unsigned)fb[(size_t)c1 * D + lane] << 16);
            float f2 = __uint_as_float((unsigned)fb[(size_t)c2 * D + lane] << 16);
            float f3 = __uint_as_float((unsigned)fb[(size_t)c3 * D + lane] << 16);
            acc = fmaf(f0, __int_as_float(b0), acc);
            acc = fmaf(f1, __int_as_float(b1), acc);
            acc = fmaf(f2, __int_as_float(b2), acc);
            acc = fmaf(f3, __int_as_float(b3), acc);
        }
        for (; k < m; ++k) {
            int c = __shfl(px, k), b = __shfl(py, k);
            acc = fmaf(__uint_as_float((unsigned)fb[(size_t)c * D + lane] << 16),
                       __int_as_float(b), acc);
        }

        // projection: out[row][lane] = relu( sum_k agg[k] * W[k][lane] )
        // agg[k] lives in lane k's acc -> constant-lane shfl (v_readlane).
        float o = 0.0f;
#pragma unroll
        for (int kk = 0; kk < D; ++kk)
            o = fmaf(__shfl(acc, kk), sW[kk * D + lane], o);

        out[(size_t)row * D + lane] = doRelu ? fmaxf(o, 0.0f) : o;
    }
}

// ---- f32 fused variant (tier-2, when fb doesn't fit) ----
template <int SLOTS>
__global__ void __launch_bounds__(256)
fused_slot_f32(const float* __restrict__ feat, const int* __restrict__ cnt,
               const int2* __restrict__ pairs, const float* __restrict__ W,
               const int* __restrict__ ovfCnt, float* __restrict__ out,
               int n_rows) {
    __shared__ float sW[D * D];
    for (int i = threadIdx.x; i < D * D; i += 256) sW[i] = W[i];
    __syncthreads();
    const int  w      = threadIdx.x >> 6;
    const int  lane   = threadIdx.x & 63;
    const bool doRelu = (*ovfCnt == 0);
    for (int row = blockIdx.x * 4 + w; row < n_rows; row += gridDim.x * 4) {
        int m = min(cnt[row], SLOTS);
        int px = 0, py = 0;
        if (lane < m) {
            int2 p = pairs[(size_t)row * SLOTS + lane];
            px = p.x; py = p.y;
        }
        float acc = 0.0f;
        int k = 0;
        for (; k + 4 <= m; k += 4) {
            int c0 = __shfl(px, k + 0), b0 = __shfl(py, k + 0);
            int c1 = __shfl(px, k + 1), b1 = __shfl(py, k + 1);
            int c2 = __shfl(px, k + 2), b2 = __shfl(py, k + 2);
            int c3 = __shfl(px, k + 3), b3 = __shfl(py, k + 3);
            float f0 = feat[(size_t)c0 * D + lane];
            float f1 = feat[(size_t)c1 * D + lane];
            float f2 = feat[(size_t)c2 * D + lane];
            float f3 = feat[(size_t)c3 * D + lane];
            acc = fmaf(f0, __int_as_float(b0), acc);
            acc = fmaf(f1, __int_as_float(b1), acc);
            acc = fmaf(f2, __int_as_float(b2), acc);
            acc = fmaf(f3, __int_as_float(b3), acc);
        }
        for (; k < m; ++k) {
            int c = __shfl(px, k), b = __shfl(py, k);
            acc = fmaf(feat[(size_t)c * D + lane], __int_as_float(b), acc);
        }
        float o = 0.0f;
#pragma unroll
        for (int kk = 0; kk < D; ++kk)
            o = fmaf(__shfl(acc, kk), sW[kk * D + lane], o);
        out[(size_t)row * D + lane] = doRelu ? fmaxf(o, 0.0f) : o;
    }
}

// ---- overflow fix-up (rare path; f32 features) ----
__global__ void __launch_bounds__(256)
ovf_kernel(const float* __restrict__ feat, const float* __restrict__ W,
           const int4* __restrict__ ovf, const int* __restrict__ ovfCnt,
           float* __restrict__ out) {
    int n = *ovfCnt;
    if (n > OVF_CAP) n = OVF_CAP;
    if (n == 0) return;
    const int lane = threadIdx.x & 63;
    const int wave = (blockIdx.x * blockDim.x + threadIdx.x) >> 6;
    const int nw   = (gridDim.x * blockDim.x) >> 6;
    for (int i = wave; i < n; i += nw) {
        int4  e = ovf[i];
        float v = __int_as_float(e.z);
        float f = feat[(size_t)e.y * D + lane];
        float acc = 0.0f;
#pragma unroll
        for (int k = 0; k < D; ++k)
            acc = fmaf(__shfl(f, k), W[k * D + lane], acc);
        unsafeAtomicAdd(&out[(size_t)e.x * D + lane], v * acc);
    }
}

__global__ void relu_fix_kernel(float* __restrict__ out,
                                const int* __restrict__ ovfCnt, int n_elems) {
    if (*ovfCnt == 0) return;
    int i = blockIdx.x * blockDim.x + threadIdx.x;
    int stride = gridDim.x * blockDim.x;
    for (; i < n_elems; i += stride)
        out[i] = fmaxf(out[i], 0.0f);
}

// ===========================================================================
// Tier-3 fallback: CSR pipeline.  Tier-4: atomic agg.
// ===========================================================================
__global__ void hist_kernel(const int* __restrict__ erows, int* __restrict__ cur,
                            int n_edges) {
    int i = blockIdx.x * blockDim.x + threadIdx.x;
    int stride = gridDim.x * blockDim.x;
    for (int e = i; e < n_edges; e += stride) atomicAdd(&cur[erows[e]], 1);
}

__global__ void __launch_bounds__(256)
scan_block_reduce(const int* __restrict__ cnt, int* __restrict__ bs, int n) {
    __shared__ int s[256];
    int i = blockIdx.x * 256 + threadIdx.x;
    s[threadIdx.x] = (i < n) ? cnt[i] : 0;
    __syncthreads();
    for (int off = 128; off > 0; off >>= 1) {
        if (threadIdx.x < (unsigned)off) s[threadIdx.x] += s[threadIdx.x + off];
        __syncthreads();
    }
    if (threadIdx.x == 0) bs[blockIdx.x] = s[0];
}

__global__ void __launch_bounds__(1024)
scan_top(int* __restrict__ bs, int nblk, int* __restrict__ rowStartN) {
    __shared__ int s[1024];
    int t = threadIdx.x;
    int x = (t < nblk) ? bs[t] : 0;
    s[t] = x;
    __syncthreads();
    for (int off = 1; off < 1024; off <<= 1) {
        int y = (t >= off) ? s[t - off] : 0;
        __syncthreads();
        s[t] += y;
        __syncthreads();
    }
    if (t < nblk) bs[t] = s[t] - x;
    if (t == 1023) *rowStartN = s[1023];
}

__global__ void __launch_bounds__(256)
scan_final(int* __restrict__ cur, const int* __restrict__ bs,
           int* __restrict__ rowStart, int n) {
    __shared__ int s[256];
    int t = threadIdx.x;
    int i = blockIdx.x * 256 + t;
    int x = (i < n) ? cur[i] : 0;
    s[t] = x;
    __syncthreads();
    for (int off = 1; off < 256; off <<= 1) {
        int y = (t >= off) ? s[t - off] : 0;
        __syncthreads();
        s[t] += y;
        __syncthreads();
    }
    int excl = s[t] - x + bs[blockIdx.x];
    if (i < n) { rowStart[i] = excl; cur[i] = excl; }
}

__global__ void scatter_kernel(const int* __restrict__ erows,
                               const int* __restrict__ ecols,
                               const float* __restrict__ evals,
                               int* __restrict__ cur, int2* __restrict__ pairs,
                               int n_edges) {
    int i = blockIdx.x * blockDim.x + threadIdx.x;
    int stride = gridDim.x * blockDim.x;
    for (int e = i; e < n_edges; e += stride) {
        int pos = atomicAdd(&cur[erows[e]], 1);
        pairs[pos] = make_int2(ecols[e], __float_as_int(evals[e]));
    }
}

__global__ void __launch_bounds__(256)
fused_kernel(const float* __restrict__ feat, const int* __restrict__ rowStart,
             const int2* __restrict__ pairs, const float* __restrict__ W,
             float* __restrict__ out, int n_rows) {
    __shared__ float sW[D * D];
    __shared__ float srow[4][D];
    for (int i = threadIdx.x; i < D * D; i += 256) sW[i] = W[i];
    const int w = threadIdx.x >> 6, lane = threadIdx.x & 63;
    const int row = blockIdx.x * 4 + w;
    float acc = 0.0f;
    if (row < n_rows) {
        int s = rowStart[row], e = rowStart[row + 1], i = s;
        for (; i + 4 <= e; i += 4) {
            int2 p0 = pairs[i + 0], p1 = pairs[i + 1];
            int2 p2 = pairs[i + 2], p3 = pairs[i + 3];
            float f0 = feat[(size_t)p0.x * D + lane];
            float f1 = feat[(size_t)p1.x * D + lane];
            float f2 = feat[(size_t)p2.x * D + lane];
            float f3 = feat[(size_t)p3.x * D + lane];
            acc = fmaf(f0, __int_as_float(p0.y), acc);
            acc = fmaf(f1, __int_as_float(p1.y), acc);
            acc = fmaf(f2, __int_as_float(p2.y), acc);
            acc = fmaf(f3, __int_as_float(p3.y), acc);
        }
        for (; i < e; ++i) {
            int2 p = pairs[i];
            acc = fmaf(feat[(size_t)p.x * D + lane], __int_as_float(p.y), acc);
        }
    }
    srow[w][lane] = acc;
    __syncthreads();
    float o = 0.0f;
#pragma unroll
    for (int k = 0; k < D; ++k) o = fmaf(srow[w][k], sW[k * D + lane], o);
    if (row < n_rows) out[(size_t)row * D + lane] = fmaxf(o, 0.0f);
}

__global__ void agg_kernel(const float* __restrict__ feat,
                           const int* __restrict__ erows,
                           const int* __restrict__ ecols,
                           const float* __restrict__ evals,
                           float* __restrict__ agg, int n_edges) {
    int gid = blockIdx.x * blockDim.x + threadIdx.x;
    int group = gid >> 4, lane4 = gid & 15;
    int stride = (gridDim.x * blockDim.x) >> 4;
    for (int e = group; e < n_edges; e += stride) {
        int r = erows[e], c = ecols[e];
        float v = evals[e];
        const float4 f = *reinterpret_cast<const float4*>(feat + (size_t)c * D + lane4 * 4);
        float* dst = agg + (size_t)r * D + lane4 * 4;
        unsafeAtomicAdd(dst + 0, f.x * v);
        unsafeAtomicAdd(dst + 1, f.y * v);
        unsafeAtomicAdd(dst + 2, f.z * v);
        unsafeAtomicAdd(dst + 3, f.w * v);
    }
}

__global__ void __launch_bounds__(256)
proj_kernel(const float* __restrict__ agg, const float* __restrict__ W,
            float* __restrict__ out, int n_rows) {
    __shared__ float sW[D * D];
    __shared__ float srow[4][D];
    for (int i = threadIdx.x; i < D * D; i += 256) sW[i] = W[i];
    __syncthreads();
    const int rg = threadIdx.x >> 6, j = threadIdx.x & 63;
    for (int row0 = blockIdx.x * 4; row0 < n_rows; row0 += gridDim.x * 4) {
        int r = row0 + rg;
        float v = (r < n_rows) ? agg[(size_t)r * D + j] : 0.0f;
        srow[rg][j] = v;
        __syncthreads();
        float acc = 0.0f;
#pragma unroll
        for (int k = 0; k < D; ++k) acc = fmaf(srow[rg][k], sW[k * D + j], acc);
        if (r < n_rows) out[(size_t)r * D + j] = fmaxf(acc, 0.0f);
        __syncthreads();
    }
}

// ===========================================================================
extern "C" void kernel_launch(void* const* d_in, const int* in_sizes, int n_in,
                              void* d_out, int out_size, void* d_ws, size_t ws_size,
                              hipStream_t stream) {
    const float* feat  = (const float*)d_in[0];
    const int*   erows = (const int*)  d_in[1];
    const int*   ecols = (const int*)  d_in[2];
    const float* evals = (const float*)d_in[3];
    const float* W     = (const float*)d_in[4];
    float*       out   = (float*)d_out;

    const int n_edges = in_sizes[1];
    const int n_nodes = in_sizes[0] / D;

    auto align256 = [](size_t x) { return (x + 255) & ~(size_t)255; };

    // ---- slot-path layout ----
    size_t off_cnt    = 0;
    size_t off_ovfCnt = align256((size_t)n_nodes * 4);
    size_t off_ovf    = align256(off_ovfCnt + 4);
    size_t off_fb     = align256(off_ovf + (size_t)OVF_CAP * 16);
    size_t off_pairs  = align256(off_fb + (size_t)n_nodes * D * 2);
    size_t need_bf16  = off_pairs + (size_t)n_nodes * 64 * 8;
    // f32 tier reuses layout without fb
    size_t off_pairs2 = off_fb;
    size_t need_f32   = off_pairs2 + (size_t)n_nodes * 64 * 8;

    const int rows_per_slice4 = (n_nodes + 3) / 4;

    if (ws_size >= need_bf16 || ws_size >= need_f32) {
        char* ws     = (char*)d_ws;
        int*  cnt    = (int*) (ws + off_cnt);
        int*  ovfCnt = (int*) (ws + off_ovfCnt);
        int4* ovf    = (int4*)(ws + off_ovf);

        hipMemsetAsync(cnt, 0, (size_t)n_nodes * 4, stream);
        hipMemsetAsync(ovfCnt, 0, 4, stream);

        if (ws_size >= need_bf16) {
            unsigned short* fb = (unsigned short*)(ws + off_fb);
            int2* pairs = (int2*)(ws + off_pairs);
            f2bf_kernel<<<2048, 256, 0, stream>>>(
                (const float4*)feat, (ushort4*)fb, n_nodes * D / 4);
            scatter_slot_kernel<64, 4><<<2048, 256, 0, stream>>>(
                erows, ecols, evals, cnt, pairs, ovf, ovfCnt, n_edges, rows_per_slice4);
            fused_slot_bf16<64><<<2048, 256, 0, stream>>>(
                fb, cnt, pairs, W, ovfCnt, out, n_nodes);
        } else {
            int2* pairs = (int2*)(ws + off_pairs2);
            scatter_slot_kernel<64, 4><<<2048, 256, 0, stream>>>(
                erows, ecols, evals, cnt, pairs, ovf, ovfCnt, n_edges, rows_per_slice4);
            fused_slot_f32<64><<<2048, 256, 0, stream>>>(
                feat, cnt, pairs, W, ovfCnt, out, n_nodes);
        }
        ovf_kernel<<<256, 256, 0, stream>>>(feat, W, ovf, ovfCnt, out);
        relu_fix_kernel<<<512, 256, 0, stream>>>(out, ovfCnt, n_nodes * D);
        return;
    }

    // ---- CSR fallback ----
    const int nblk = (n_nodes + 255) / 256;
    size_t off_rowStart = 0;
    size_t off_cur      = align256(off_rowStart + (size_t)(n_nodes + 1) * 4);
    size_t off_bs       = align256(off_cur + (size_t)n_nodes * 4);
    size_t off_p        = align256(off_bs + (size_t)nblk * 4);
    size_t ws_needed    = off_p + (size_t)n_edges * 8;

    if (ws_size >= ws_needed && nblk <= 1024) {
        char* ws = (char*)d_ws;
        int*  rowStart = (int*) (ws + off_rowStart);
        int*  cur      = (int*) (ws + off_cur);
        int*  bs       = (int*) (ws + off_bs);
        int2* pairs    = (int2*)(ws + off_p);

        hipMemsetAsync(cur, 0, (size_t)n_nodes * 4, stream);
        hist_kernel<<<2048, 256, 0, stream>>>(erows, cur, n_edges);
        scan_block_reduce<<<nblk, 256, 0, stream>>>(cur, bs, n_nodes);
        scan_top<<<1, 1024, 0, stream>>>(bs, nblk, rowStart + n_nodes);
        scan_final<<<nblk, 256, 0, stream>>>(cur, bs, rowStart, n_nodes);
        scatter_kernel<<<2048, 256, 0, stream>>>(erows, ecols, evals, cur, pairs, n_edges);
        fused_kernel<<<(n_nodes + 3) / 4, 256, 0, stream>>>(feat, rowStart, pairs, W, out, n_nodes);
    } else {
        hipMemsetAsync(out, 0, (size_t)n_nodes * D * 4, stream);
        agg_kernel<<<2048, 256, 0, stream>>>(feat, erows, ecols, evals, out, n_edges);
        proj_kernel<<<2048, 256, 0, stream>>>(out, W, out, n_nodes);
    }
}

// Round 10
// 295.227 us; speedup vs baseline: 1.0121x; 1.0121x over previous
//
#include <hip/hip_runtime.h>

#define D 64
#define OVF_CAP 65536

// ===========================================================================
// ws layout (256B aligned):
//   cnt    : N int          — per-row degree counter (memset 0 each call)
//   ovfCnt : 1 int          — overflow edge count    (memset 0 each call)
//   ovf    : OVF_CAP int4   — overflow edges (r, c, val_bits, _)
//   fb     : N*D ushort     — bf16 copy of features
//   pairs  : N*SLOTS int2   — (col, val_bits) for row r at pairs[r*SLOTS+k]
// SLOTS=32: pairs = 25.6MB -> 3.2MB per XCD row-slice, fits 4MB L2 (write
// locality).  P[deg>32] ~ 1e-4 for Poisson(16); ovf path covers the rest.
// ===========================================================================

__device__ inline unsigned short f32_to_bf16_rne(float x) {
    unsigned u = __float_as_uint(x);
    unsigned r = (u + 0x7FFFu + ((u >> 16) & 1u)) >> 16;
    return (unsigned short)r;
}

// ---- features f32 -> bf16 (vectorized) ----
__global__ void f2bf_kernel(const float4* __restrict__ in,
                            ushort4* __restrict__ out, int n4) {
    int i = blockIdx.x * blockDim.x + threadIdx.x;
    int stride = gridDim.x * blockDim.x;
    for (; i < n4; i += stride) {
        float4 f = in[i];
        ushort4 u;
        u.x = f32_to_bf16_rne(f.x);
        u.y = f32_to_bf16_rne(f.y);
        u.z = f32_to_bf16_rne(f.z);
        u.w = f32_to_bf16_rne(f.w);
        out[i] = u;
    }
}

// ---- slot scatter: NSLICE row-slices (XCD/L2 write locality), 4-way unroll --
template <int SLOTS, int NSLICE>
__global__ void scatter_slot_kernel(const int* __restrict__ erows,
                                    const int* __restrict__ ecols,
                                    const float* __restrict__ evals,
                                    int* __restrict__ cnt,
                                    int2* __restrict__ pairs,
                                    int4* __restrict__ ovf,
                                    int* __restrict__ ovfCnt,
                                    int n_edges, int rows_per_slice) {
    const int slice = blockIdx.x & (NSLICE - 1);
    const int rlo   = slice * rows_per_slice;
    const int rhi   = rlo + rows_per_slice;
    const int sub   = blockIdx.x / NSLICE;
    const int t     = sub * blockDim.x + threadIdx.x;
    const int strid = (gridDim.x / NSLICE) * blockDim.x;

    auto handle = [&](int r, int c, float v) {
        if (r >= rlo && r < rhi) {
            int pos = atomicAdd(&cnt[r], 1);
            if (pos < SLOTS) {
                pairs[(size_t)r * SLOTS + pos] = make_int2(c, __float_as_int(v));
            } else {
                int oi = atomicAdd(ovfCnt, 1);
                if (oi < OVF_CAP) ovf[oi] = make_int4(r, c, __float_as_int(v), 0);
            }
        }
    };

    int e = t;
    for (; e + 3 * strid < n_edges; e += 4 * strid) {
        int e0 = e, e1 = e + strid, e2 = e + 2 * strid, e3 = e + 3 * strid;
        int   r0 = erows[e0], r1 = erows[e1], r2 = erows[e2], r3 = erows[e3];
        int   c0 = ecols[e0], c1 = ecols[e1], c2 = ecols[e2], c3 = ecols[e3];
        float v0 = evals[e0], v1 = evals[e1], v2 = evals[e2], v3 = evals[e3];
        handle(r0, c0, v0);
        handle(r1, c1, v1);
        handle(r2, c2, v2);
        handle(r3, c3, v3);
    }
    for (; e < n_edges; e += strid)
        handle(erows[e], ecols[e], evals[e]);
}

// ---- fused gather(bf16) + aggregate + project + relu.  Round-5 structure:
//      one row-quad per block (no grid-stride), srow-LDS projection.
//      VGPR ~36 -> ~8 waves/SIMD for max gather-latency hiding. ----
template <int SLOTS>
__global__ void __launch_bounds__(256)
fused_slot_bf16(const unsigned short* __restrict__ fb,
                const int* __restrict__ cnt, const int2* __restrict__ pairs,
                const float* __restrict__ W, const int* __restrict__ ovfCnt,
                float* __restrict__ out, int n_rows) {
    __shared__ float sW[D * D];   // 16 KB
    __shared__ float srow[4][D];

    for (int i = threadIdx.x; i < D * D; i += 256)
        sW[i] = W[i];

    const int  w      = threadIdx.x >> 6;
    const int  lane   = threadIdx.x & 63;
    const int  row    = blockIdx.x * 4 + w;
    const bool doRelu = (*ovfCnt == 0);

    float acc = 0.0f;
    if (row < n_rows) {
        int m = min(cnt[row], SLOTS);
        int px = 0, py = 0;
        if (lane < m) {                        // only filled slots touched
            int2 p = pairs[(size_t)row * SLOTS + lane];
            px = p.x; py = p.y;
        }
        int k = 0;
        for (; k + 4 <= m; k += 4) {
            int c0 = __shfl(px, k + 0), b0 = __shfl(py, k + 0);
            int c1 = __shfl(px, k + 1), b1 = __shfl(py, k + 1);
            int c2 = __shfl(px, k + 2), b2 = __shfl(py, k + 2);
            int c3 = __shfl(px, k + 3), b3 = __shfl(py, k + 3);
            float f0 = __uint_as_float((unsigned)fb[(size_t)c0 * D + lane] << 16);
            float f1 = __uint_as_float((unsigned)fb[(size_t)c1 * D + lane] << 16);
            float f2 = __uint_as_float((unsigned)fb[(size_t)c2 * D + lane] << 16);
            float f3 = __uint_as_float((unsigned)fb[(size_t)c3 * D + lane] << 16);
            acc = fmaf(f0, __int_as_float(b0), acc);
            acc = fmaf(f1, __int_as_float(b1), acc);
            acc = fmaf(f2, __int_as_float(b2), acc);
            acc = fmaf(f3, __int_as_float(b3), acc);
        }
        for (; k < m; ++k) {
            int c = __shfl(px, k), b = __shfl(py, k);
            acc = fmaf(__uint_as_float((unsigned)fb[(size_t)c * D + lane] << 16),
                       __int_as_float(b), acc);
        }
    }
    srow[w][lane] = acc;
    __syncthreads();   // covers sW staging AND srow writes

    float o = 0.0f;
#pragma unroll
    for (int kk = 0; kk < D; ++kk)
        o = fmaf(srow[w][kk], sW[kk * D + lane], o);

    if (row < n_rows)
        out[(size_t)row * D + lane] = doRelu ? fmaxf(o, 0.0f) : o;
}

// ---- f32 fused variant (tier-2, when fb doesn't fit) ----
template <int SLOTS>
__global__ void __launch_bounds__(256)
fused_slot_f32(const float* __restrict__ feat, const int* __restrict__ cnt,
               const int2* __restrict__ pairs, const float* __restrict__ W,
               const int* __restrict__ ovfCnt, float* __restrict__ out,
               int n_rows) {
    __shared__ float sW[D * D];
    __shared__ float srow[4][D];
    for (int i = threadIdx.x; i < D * D; i += 256) sW[i] = W[i];
    const int  w      = threadIdx.x >> 6;
    const int  lane   = threadIdx.x & 63;
    const int  row    = blockIdx.x * 4 + w;
    const bool doRelu = (*ovfCnt == 0);
    float acc = 0.0f;
    if (row < n_rows) {
        int m = min(cnt[row], SLOTS);
        int px = 0, py = 0;
        if (lane < m) {
            int2 p = pairs[(size_t)row * SLOTS + lane];
            px = p.x; py = p.y;
        }
        int k = 0;
        for (; k + 4 <= m; k += 4) {
            int c0 = __shfl(px, k + 0), b0 = __shfl(py, k + 0);
            int c1 = __shfl(px, k + 1), b1 = __shfl(py, k + 1);
            int c2 = __shfl(px, k + 2), b2 = __shfl(py, k + 2);
            int c3 = __shfl(px, k + 3), b3 = __shfl(py, k + 3);
            float f0 = feat[(size_t)c0 * D + lane];
            float f1 = feat[(size_t)c1 * D + lane];
            float f2 = feat[(size_t)c2 * D + lane];
            float f3 = feat[(size_t)c3 * D + lane];
            acc = fmaf(f0, __int_as_float(b0), acc);
            acc = fmaf(f1, __int_as_float(b1), acc);
            acc = fmaf(f2, __int_as_float(b2), acc);
            acc = fmaf(f3, __int_as_float(b3), acc);
        }
        for (; k < m; ++k) {
            int c = __shfl(px, k), b = __shfl(py, k);
            acc = fmaf(feat[(size_t)c * D + lane], __int_as_float(b), acc);
        }
    }
    srow[w][lane] = acc;
    __syncthreads();
    float o = 0.0f;
#pragma unroll
    for (int kk = 0; kk < D; ++kk)
        o = fmaf(srow[w][kk], sW[kk * D + lane], o);
    if (row < n_rows)
        out[(size_t)row * D + lane] = doRelu ? fmaxf(o, 0.0f) : o;
}

// ---- overflow fix-up (rare path; f32 features) ----
__global__ void __launch_bounds__(256)
ovf_kernel(const float* __restrict__ feat, const float* __restrict__ W,
           const int4* __restrict__ ovf, const int* __restrict__ ovfCnt,
           float* __restrict__ out) {
    int n = *ovfCnt;
    if (n > OVF_CAP) n = OVF_CAP;
    if (n == 0) return;
    const int lane = threadIdx.x & 63;
    const int wave = (blockIdx.x * blockDim.x + threadIdx.x) >> 6;
    const int nw   = (gridDim.x * blockDim.x) >> 6;
    for (int i = wave; i < n; i += nw) {
        int4  e = ovf[i];
        float v = __int_as_float(e.z);
        float f = feat[(size_t)e.y * D + lane];
        float acc = 0.0f;
#pragma unroll
        for (int k = 0; k < D; ++k)
            acc = fmaf(__shfl(f, k), W[k * D + lane], acc);
        unsafeAtomicAdd(&out[(size_t)e.x * D + lane], v * acc);
    }
}

__global__ void relu_fix_kernel(float* __restrict__ out,
                                const int* __restrict__ ovfCnt, int n_elems) {
    if (*ovfCnt == 0) return;
    int i = blockIdx.x * blockDim.x + threadIdx.x;
    int stride = gridDim.x * blockDim.x;
    for (; i < n_elems; i += stride)
        out[i] = fmaxf(out[i], 0.0f);
}

// ===========================================================================
// Tier-3 fallback: CSR pipeline.  Tier-4: atomic agg.
// ===========================================================================
__global__ void hist_kernel(const int* __restrict__ erows, int* __restrict__ cur,
                            int n_edges) {
    int i = blockIdx.x * blockDim.x + threadIdx.x;
    int stride = gridDim.x * blockDim.x;
    for (int e = i; e < n_edges; e += stride) atomicAdd(&cur[erows[e]], 1);
}

__global__ void __launch_bounds__(256)
scan_block_reduce(const int* __restrict__ cnt, int* __restrict__ bs, int n) {
    __shared__ int s[256];
    int i = blockIdx.x * 256 + threadIdx.x;
    s[threadIdx.x] = (i < n) ? cnt[i] : 0;
    __syncthreads();
    for (int off = 128; off > 0; off >>= 1) {
        if (threadIdx.x < (unsigned)off) s[threadIdx.x] += s[threadIdx.x + off];
        __syncthreads();
    }
    if (threadIdx.x == 0) bs[blockIdx.x] = s[0];
}

__global__ void __launch_bounds__(1024)
scan_top(int* __restrict__ bs, int nblk, int* __restrict__ rowStartN) {
    __shared__ int s[1024];
    int t = threadIdx.x;
    int x = (t < nblk) ? bs[t] : 0;
    s[t] = x;
    __syncthreads();
    for (int off = 1; off < 1024; off <<= 1) {
        int y = (t >= off) ? s[t - off] : 0;
        __syncthreads();
        s[t] += y;
        __syncthreads();
    }
    if (t < nblk) bs[t] = s[t] - x;
    if (t == 1023) *rowStartN = s[1023];
}

__global__ void __launch_bounds__(256)
scan_final(int* __restrict__ cur, const int* __restrict__ bs,
           int* __restrict__ rowStart, int n) {
    __shared__ int s[256];
    int t = threadIdx.x;
    int i = blockIdx.x * 256 + t;
    int x = (i < n) ? cur[i] : 0;
    s[t] = x;
    __syncthreads();
    for (int off = 1; off < 256; off <<= 1) {
        int y = (t >= off) ? s[t - off] : 0;
        __syncthreads();
        s[t] += y;
        __syncthreads();
    }
    int excl = s[t] - x + bs[blockIdx.x];
    if (i < n) { rowStart[i] = excl; cur[i] = excl; }
}

__global__ void scatter_kernel(const int* __restrict__ erows,
                               const int* __restrict__ ecols,
                               const float* __restrict__ evals,
                               int* __restrict__ cur, int2* __restrict__ pairs,
                               int n_edges) {
    int i = blockIdx.x * blockDim.x + threadIdx.x;
    int stride = gridDim.x * blockDim.x;
    for (int e = i; e < n_edges; e += stride) {
        int pos = atomicAdd(&cur[erows[e]], 1);
        pairs[pos] = make_int2(ecols[e], __float_as_int(evals[e]));
    }
}

__global__ void __launch_bounds__(256)
fused_kernel(const float* __restrict__ feat, const int* __restrict__ rowStart,
             const int2* __restrict__ pairs, const float* __restrict__ W,
             float* __restrict__ out, int n_rows) {
    __shared__ float sW[D * D];
    __shared__ float srow[4][D];
    for (int i = threadIdx.x; i < D * D; i += 256) sW[i] = W[i];
    const int w = threadIdx.x >> 6, lane = threadIdx.x & 63;
    const int row = blockIdx.x * 4 + w;
    float acc = 0.0f;
    if (row < n_rows) {
        int s = rowStart[row], e = rowStart[row + 1], i = s;
        for (; i + 4 <= e; i += 4) {
            int2 p0 = pairs[i + 0], p1 = pairs[i + 1];
            int2 p2 = pairs[i + 2], p3 = pairs[i + 3];
            float f0 = feat[(size_t)p0.x * D + lane];
            float f1 = feat[(size_t)p1.x * D + lane];
            float f2 = feat[(size_t)p2.x * D + lane];
            float f3 = feat[(size_t)p3.x * D + lane];
            acc = fmaf(f0, __int_as_float(p0.y), acc);
            acc = fmaf(f1, __int_as_float(p1.y), acc);
            acc = fmaf(f2, __int_as_float(p2.y), acc);
            acc = fmaf(f3, __int_as_float(p3.y), acc);
        }
        for (; i < e; ++i) {
            int2 p = pairs[i];
            acc = fmaf(feat[(size_t)p.x * D + lane], __int_as_float(p.y), acc);
        }
    }
    srow[w][lane] = acc;
    __syncthreads();
    float o = 0.0f;
#pragma unroll
    for (int k = 0; k < D; ++k) o = fmaf(srow[w][k], sW[k * D + lane], o);
    if (row < n_rows) out[(size_t)row * D + lane] = fmaxf(o, 0.0f);
}

__global__ void agg_kernel(const float* __restrict__ feat,
                           const int* __restrict__ erows,
                           const int* __restrict__ ecols,
                           const float* __restrict__ evals,
                           float* __restrict__ agg, int n_edges) {
    int gid = blockIdx.x * blockDim.x + threadIdx.x;
    int group = gid >> 4, lane4 = gid & 15;
    int stride = (gridDim.x * blockDim.x) >> 4;
    for (int e = group; e < n_edges; e += stride) {
        int r = erows[e], c = ecols[e];
        float v = evals[e];
        const float4 f = *reinterpret_cast<const float4*>(feat + (size_t)c * D + lane4 * 4);
        float* dst = agg + (size_t)r * D + lane4 * 4;
        unsafeAtomicAdd(dst + 0, f.x * v);
        unsafeAtomicAdd(dst + 1, f.y * v);
        unsafeAtomicAdd(dst + 2, f.z * v);
        unsafeAtomicAdd(dst + 3, f.w * v);
    }
}

__global__ void __launch_bounds__(256)
proj_kernel(const float* __restrict__ agg, const float* __restrict__ W,
            float* __restrict__ out, int n_rows) {
    __shared__ float sW[D * D];
    __shared__ float srow[4][D];
    for (int i = threadIdx.x; i < D * D; i += 256) sW[i] = W[i];
    __syncthreads();
    const int rg = threadIdx.x >> 6, j = threadIdx.x & 63;
    for (int row0 = blockIdx.x * 4; row0 < n_rows; row0 += gridDim.x * 4) {
        int r = row0 + rg;
        float v = (r < n_rows) ? agg[(size_t)r * D + j] : 0.0f;
        srow[rg][j] = v;
        __syncthreads();
        float acc = 0.0f;
#pragma unroll
        for (int k = 0; k < D; ++k) acc = fmaf(srow[rg][k], sW[k * D + j], acc);
        if (r < n_rows) out[(size_t)r * D + j] = fmaxf(acc, 0.0f);
        __syncthreads();
    }
}

// ===========================================================================
extern "C" void kernel_launch(void* const* d_in, const int* in_sizes, int n_in,
                              void* d_out, int out_size, void* d_ws, size_t ws_size,
                              hipStream_t stream) {
    const float* feat  = (const float*)d_in[0];
    const int*   erows = (const int*)  d_in[1];
    const int*   ecols = (const int*)  d_in[2];
    const float* evals = (const float*)d_in[3];
    const float* W     = (const float*)d_in[4];
    float*       out   = (float*)d_out;

    const int n_edges = in_sizes[1];
    const int n_nodes = in_sizes[0] / D;

    auto align256 = [](size_t x) { return (x + 255) & ~(size_t)255; };

    // ---- slot-path layout (SLOTS=32) ----
    size_t off_cnt    = 0;
    size_t off_ovfCnt = align256((size_t)n_nodes * 4);
    size_t off_ovf    = align256(off_ovfCnt + 4);
    size_t off_fb     = align256(off_ovf + (size_t)OVF_CAP * 16);
    size_t off_pairs  = align256(off_fb + (size_t)n_nodes * D * 2);
    size_t need_bf16  = off_pairs + (size_t)n_nodes * 32 * 8;
    // f32 tier reuses layout without fb
    size_t off_pairs2 = off_fb;
    size_t need_f32   = off_pairs2 + (size_t)n_nodes * 32 * 8;

    const int rows_per_slice8 = (n_nodes + 7) / 8;
    const int nblk_fused      = (n_nodes + 3) / 4;

    if (ws_size >= need_bf16 || ws_size >= need_f32) {
        char* ws     = (char*)d_ws;
        int*  cnt    = (int*) (ws + off_cnt);
        int*  ovfCnt = (int*) (ws + off_ovfCnt);
        int4* ovf    = (int4*)(ws + off_ovf);

        hipMemsetAsync(cnt, 0, (size_t)n_nodes * 4, stream);
        hipMemsetAsync(ovfCnt, 0, 4, stream);

        if (ws_size >= need_bf16) {
            unsigned short* fb = (unsigned short*)(ws + off_fb);
            int2* pairs = (int2*)(ws + off_pairs);
            f2bf_kernel<<<2048, 256, 0, stream>>>(
                (const float4*)feat, (ushort4*)fb, n_nodes * D / 4);
            scatter_slot_kernel<32, 8><<<2048, 256, 0, stream>>>(
                erows, ecols, evals, cnt, pairs, ovf, ovfCnt, n_edges, rows_per_slice8);
            fused_slot_bf16<32><<<nblk_fused, 256, 0, stream>>>(
                fb, cnt, pairs, W, ovfCnt, out, n_nodes);
        } else {
            int2* pairs = (int2*)(ws + off_pairs2);
            scatter_slot_kernel<32, 8><<<2048, 256, 0, stream>>>(
                erows, ecols, evals, cnt, pairs, ovf, ovfCnt, n_edges, rows_per_slice8);
            fused_slot_f32<32><<<nblk_fused, 256, 0, stream>>>(
                feat, cnt, pairs, W, ovfCnt, out, n_nodes);
        }
        ovf_kernel<<<256, 256, 0, stream>>>(feat, W, ovf, ovfCnt, out);
        relu_fix_kernel<<<512, 256, 0, stream>>>(out, ovfCnt, n_nodes * D);
        return;
    }

    // ---- CSR fallback ----
    const int nblk = (n_nodes + 255) / 256;
    size_t off_rowStart = 0;
    size_t off_cur      = align256(off_rowStart + (size_t)(n_nodes + 1) * 4);
    size_t off_bs       = align256(off_cur + (size_t)n_nodes * 4);
    size_t off_p        = align256(off_bs + (size_t)nblk * 4);
    size_t ws_needed    = off_p + (size_t)n_edges * 8;

    if (ws_size >= ws_needed && nblk <= 1024) {
        char* ws = (char*)d_ws;
        int*  rowStart = (int*) (ws + off_rowStart);
        int*  cur      = (int*) (ws + off_cur);
        int*  bs       = (int*) (ws + off_bs);
        int2* pairs    = (int2*)(ws + off_p);

        hipMemsetAsync(cur, 0, (size_t)n_nodes * 4, stream);
        hist_kernel<<<2048, 256, 0, stream>>>(erows, cur, n_edges);
        scan_block_reduce<<<nblk, 256, 0, stream>>>(cur, bs, n_nodes);
        scan_top<<<1, 1024, 0, stream>>>(bs, nblk, rowStart + n_nodes);
        scan_final<<<nblk, 256, 0, stream>>>(cur, bs, rowStart, n_nodes);
        scatter_kernel<<<2048, 256, 0, stream>>>(erows, ecols, evals, cur, pairs, n_edges);
        fused_kernel<<<(n_nodes + 3) / 4, 256, 0, stream>>>(feat, rowStart, pairs, W, out, n_nodes);
    } else {
        hipMemsetAsync(out, 0, (size_t)n_nodes * D * 4, stream);
        agg_kernel<<<2048, 256, 0, stream>>>(feat, erows, ecols, evals, out, n_edges);
        proj_kernel<<<2048, 256, 0, stream>>>(out, W, out, n_nodes);
    }
}

// Round 11
// 273.050 us; speedup vs baseline: 1.0943x; 1.0812x over previous
//
#include <hip/hip_runtime.h>

#define D 64
#define OVF_CAP 65536

// ===========================================================================
// out = relu((A @ F) @ W) = relu(A @ (F @ W))   [matmul associativity]
//
// Pipeline (tier-1): gw: G=bf16(F@W) -> slot-scatter edges by row ->
//                    fused gather-sum over G -> (rare) ovf fixup + relu fix.
// ws layout (256B aligned):
//   cnt    : N int          — per-row degree counter (memset 0 each call)
//   ovfCnt : 1 int          — overflow edge count    (memset 0 each call)
//   ovf    : OVF_CAP int4   — overflow edges (r, c, val_bits, _)
//   G      : N*D ushort     — bf16 of (F @ W)
//   pairs  : N*SLOTS int2   — (col, val_bits) for row r at pairs[r*SLOTS+k]
// ===========================================================================

__device__ inline unsigned short f32_to_bf16_rne(float x) {
    unsigned u = __float_as_uint(x);
    unsigned r = (u + 0x7FFFu + ((u >> 16) & 1u)) >> 16;
    return (unsigned short)r;
}
__device__ inline float bf16_to_f32(unsigned short h) {
    return __uint_as_float((unsigned)h << 16);
}

// ---- G = bf16(F @ W).  Grid-stride; sW staged once per block. ----
__global__ void __launch_bounds__(256)
gw_kernel(const float* __restrict__ feat, const float* __restrict__ W,
          unsigned short* __restrict__ G, int n_rows) {
    __shared__ float sW[D * D];   // 16 KB
    __shared__ float srow[4][D];
    for (int i = threadIdx.x; i < D * D; i += 256) sW[i] = W[i];
    __syncthreads();
    const int rg = threadIdx.x >> 6, j = threadIdx.x & 63;
    for (int row0 = blockIdx.x * 4; row0 < n_rows; row0 += gridDim.x * 4) {
        int r = row0 + rg;
        float v = (r < n_rows) ? feat[(size_t)r * D + j] : 0.0f;
        srow[rg][j] = v;
        __syncthreads();
        float acc = 0.0f;
#pragma unroll
        for (int k = 0; k < D; ++k) acc = fmaf(srow[rg][k], sW[k * D + j], acc);
        if (r < n_rows) G[(size_t)r * D + j] = f32_to_bf16_rne(acc);
        __syncthreads();
    }
}

// ---- slot scatter: 8 row-slices; scan erows only, fetch c/v on demand ----
template <int SLOTS, int NSLICE>
__global__ void scatter_slot_kernel(const int* __restrict__ erows,
                                    const int* __restrict__ ecols,
                                    const float* __restrict__ evals,
                                    int* __restrict__ cnt,
                                    int2* __restrict__ pairs,
                                    int4* __restrict__ ovf,
                                    int* __restrict__ ovfCnt,
                                    int n_edges, int rows_per_slice) {
    const int slice = blockIdx.x & (NSLICE - 1);
    const int rlo   = slice * rows_per_slice;
    const int rhi   = rlo + rows_per_slice;
    const int sub   = blockIdx.x / NSLICE;
    const int t     = sub * blockDim.x + threadIdx.x;
    const int strid = (gridDim.x / NSLICE) * blockDim.x;

    auto handle = [&](int e, int r) {
        int   c = ecols[e];
        float v = evals[e];
        int pos = atomicAdd(&cnt[r], 1);
        if (pos < SLOTS) {
            pairs[(size_t)r * SLOTS + pos] = make_int2(c, __float_as_int(v));
        } else {
            int oi = atomicAdd(ovfCnt, 1);
            if (oi < OVF_CAP) ovf[oi] = make_int4(r, c, __float_as_int(v), 0);
        }
    };

    int e = t;
    for (; e + 3 * strid < n_edges; e += 4 * strid) {
        int r0 = erows[e];
        int r1 = erows[e + strid];
        int r2 = erows[e + 2 * strid];
        int r3 = erows[e + 3 * strid];
        if (r0 >= rlo && r0 < rhi) handle(e, r0);
        if (r1 >= rlo && r1 < rhi) handle(e + strid, r1);
        if (r2 >= rlo && r2 < rhi) handle(e + 2 * strid, r2);
        if (r3 >= rlo && r3 < rhi) handle(e + 3 * strid, r3);
    }
    for (; e < n_edges; e += strid) {
        int r = erows[e];
        if (r >= rlo && r < rhi) handle(e, r);
    }
}

// ---- fused gather-sum over G.  LDS-free; 2 rows per wave; one coalesced
//      512B pairs load covers both rows (lanes 0-31: row r0, 32-63: r0+1).
//      Padded slots get b=0 (and c=0 -> harmless G[0] read). ----
template <int SLOTS>
__global__ void __launch_bounds__(256)
fused_gather2(const unsigned short* __restrict__ G, const int* __restrict__ cnt,
              const int2* __restrict__ pairs, const int* __restrict__ ovfCnt,
              float* __restrict__ out, int n_rows) {
    const int  lane   = threadIdx.x & 63;
    const int  slot   = lane & (SLOTS - 1);
    const int  half   = lane >> 5;          // 0 -> row r0, 1 -> row r0+1
    const int  wid    = (blockIdx.x * blockDim.x + threadIdx.x) >> 6;
    const int  nw     = (gridDim.x * blockDim.x) >> 6;
    const bool doRelu = (*ovfCnt == 0);

    for (int base = wid * 2; base < n_rows; base += nw * 2) {
        const int r0 = base, r1 = base + 1;
        int m0 = min(cnt[r0], SLOTS);
        int m1 = (r1 < n_rows) ? min(cnt[r1], SLOTS) : 0;

        int2 p = make_int2(0, 0);
        if (r0 + half < n_rows)
            p = pairs[(size_t)r0 * SLOTS + lane];   // contiguous: covers r0,r1
        const int mh = half ? m1 : m0;
        int px = (slot < mh) ? p.x : 0;
        int py = (slot < mh) ? p.y : 0;

        float acc0 = 0.0f, acc1 = 0.0f;
        const int mm = max(m0, m1);
        int k = 0;
        for (; k + 4 <= mm; k += 4) {
#pragma unroll
            for (int u = 0; u < 4; u += 2) {
                int cA0 = __shfl(px, k + u),          bA0 = __shfl(py, k + u);
                int cB0 = __shfl(px, 32 + k + u),     bB0 = __shfl(py, 32 + k + u);
                int cA1 = __shfl(px, k + u + 1),      bA1 = __shfl(py, k + u + 1);
                int cB1 = __shfl(px, 32 + k + u + 1), bB1 = __shfl(py, 32 + k + u + 1);
                float fA0 = bf16_to_f32(G[(size_t)cA0 * D + lane]);
                float fB0 = bf16_to_f32(G[(size_t)cB0 * D + lane]);
                float fA1 = bf16_to_f32(G[(size_t)cA1 * D + lane]);
                float fB1 = bf16_to_f32(G[(size_t)cB1 * D + lane]);
                acc0 = fmaf(fA0, __int_as_float(bA0), acc0);
                acc1 = fmaf(fB0, __int_as_float(bB0), acc1);
                acc0 = fmaf(fA1, __int_as_float(bA1), acc0);
                acc1 = fmaf(fB1, __int_as_float(bB1), acc1);
            }
        }
        for (; k < mm; ++k) {
            int cA = __shfl(px, k),      bA = __shfl(py, k);
            int cB = __shfl(px, 32 + k), bB = __shfl(py, 32 + k);
            float fA = bf16_to_f32(G[(size_t)cA * D + lane]);
            float fB = bf16_to_f32(G[(size_t)cB * D + lane]);
            acc0 = fmaf(fA, __int_as_float(bA), acc0);
            acc1 = fmaf(fB, __int_as_float(bB), acc1);
        }

        out[(size_t)r0 * D + lane] = doRelu ? fmaxf(acc0, 0.0f) : acc0;
        if (r1 < n_rows)
            out[(size_t)r1 * D + lane] = doRelu ? fmaxf(acc1, 0.0f) : acc1;
    }
}

// ---- overflow fix-up (tier-1, via G): out[r] += v * G[c] ----
__global__ void __launch_bounds__(256)
ovf_kernel_g(const unsigned short* __restrict__ G, const int4* __restrict__ ovf,
             const int* __restrict__ ovfCnt, float* __restrict__ out) {
    int n = *ovfCnt;
    if (n > OVF_CAP) n = OVF_CAP;
    if (n == 0) return;
    const int lane = threadIdx.x & 63;
    const int wave = (blockIdx.x * blockDim.x + threadIdx.x) >> 6;
    const int nw   = (gridDim.x * blockDim.x) >> 6;
    for (int i = wave; i < n; i += nw) {
        int4  e = ovf[i];
        float g = bf16_to_f32(G[(size_t)e.y * D + lane]);
        unsafeAtomicAdd(&out[(size_t)e.x * D + lane], __int_as_float(e.z) * g);
    }
}

// ---- overflow fix-up (tier-2, via feat/W) ----
__global__ void __launch_bounds__(256)
ovf_kernel_fw(const float* __restrict__ feat, const float* __restrict__ W,
              const int4* __restrict__ ovf, const int* __restrict__ ovfCnt,
              float* __restrict__ out) {
    int n = *ovfCnt;
    if (n > OVF_CAP) n = OVF_CAP;
    if (n == 0) return;
    const int lane = threadIdx.x & 63;
    const int wave = (blockIdx.x * blockDim.x + threadIdx.x) >> 6;
    const int nw   = (gridDim.x * blockDim.x) >> 6;
    for (int i = wave; i < n; i += nw) {
        int4  e = ovf[i];
        float v = __int_as_float(e.z);
        float f = feat[(size_t)e.y * D + lane];
        float acc = 0.0f;
#pragma unroll
        for (int k = 0; k < D; ++k)
            acc = fmaf(__shfl(f, k), W[k * D + lane], acc);
        unsafeAtomicAdd(&out[(size_t)e.x * D + lane], v * acc);
    }
}

__global__ void relu_fix_kernel(float* __restrict__ out,
                                const int* __restrict__ ovfCnt, int n_elems) {
    if (*ovfCnt == 0) return;
    int i = blockIdx.x * blockDim.x + threadIdx.x;
    int stride = gridDim.x * blockDim.x;
    for (; i < n_elems; i += stride)
        out[i] = fmaxf(out[i], 0.0f);
}

// ---- tier-2 fused (f32 feat gather + LDS projection; when G doesn't fit) ----
template <int SLOTS>
__global__ void __launch_bounds__(256)
fused_slot_f32(const float* __restrict__ feat, const int* __restrict__ cnt,
               const int2* __restrict__ pairs, const float* __restrict__ W,
               const int* __restrict__ ovfCnt, float* __restrict__ out,
               int n_rows) {
    __shared__ float sW[D * D];
    __shared__ float srow[4][D];
    for (int i = threadIdx.x; i < D * D; i += 256) sW[i] = W[i];
    const int  w      = threadIdx.x >> 6;
    const int  lane   = threadIdx.x & 63;
    const int  row    = blockIdx.x * 4 + w;
    const bool doRelu = (*ovfCnt == 0);
    float acc = 0.0f;
    if (row < n_rows) {
        int m = min(cnt[row], SLOTS);
        int px = 0, py = 0;
        if (lane < m) {
            int2 p = pairs[(size_t)row * SLOTS + lane];
            px = p.x; py = p.y;
        }
        int k = 0;
        for (; k + 4 <= m; k += 4) {
            int c0 = __shfl(px, k + 0), b0 = __shfl(py, k + 0);
            int c1 = __shfl(px, k + 1), b1 = __shfl(py, k + 1);
            int c2 = __shfl(px, k + 2), b2 = __shfl(py, k + 2);
            int c3 = __shfl(px, k + 3), b3 = __shfl(py, k + 3);
            float f0 = feat[(size_t)c0 * D + lane];
            float f1 = feat[(size_t)c1 * D + lane];
            float f2 = feat[(size_t)c2 * D + lane];
            float f3 = feat[(size_t)c3 * D + lane];
            acc = fmaf(f0, __int_as_float(b0), acc);
            acc = fmaf(f1, __int_as_float(b1), acc);
            acc = fmaf(f2, __int_as_float(b2), acc);
            acc = fmaf(f3, __int_as_float(b3), acc);
        }
        for (; k < m; ++k) {
            int c = __shfl(px, k), b = __shfl(py, k);
            acc = fmaf(feat[(size_t)c * D + lane], __int_as_float(b), acc);
        }
    }
    srow[w][lane] = acc;
    __syncthreads();
    float o = 0.0f;
#pragma unroll
    for (int kk = 0; kk < D; ++kk)
        o = fmaf(srow[w][kk], sW[kk * D + lane], o);
    if (row < n_rows)
        out[(size_t)row * D + lane] = doRelu ? fmaxf(o, 0.0f) : o;
}

// ===========================================================================
// Tier-3 fallback: CSR pipeline.  Tier-4: atomic agg.
// ===========================================================================
__global__ void hist_kernel(const int* __restrict__ erows, int* __restrict__ cur,
                            int n_edges) {
    int i = blockIdx.x * blockDim.x + threadIdx.x;
    int stride = gridDim.x * blockDim.x;
    for (int e = i; e < n_edges; e += stride) atomicAdd(&cur[erows[e]], 1);
}

__global__ void __launch_bounds__(256)
scan_block_reduce(const int* __restrict__ cnt, int* __restrict__ bs, int n) {
    __shared__ int s[256];
    int i = blockIdx.x * 256 + threadIdx.x;
    s[threadIdx.x] = (i < n) ? cnt[i] : 0;
    __syncthreads();
    for (int off = 128; off > 0; off >>= 1) {
        if (threadIdx.x < (unsigned)off) s[threadIdx.x] += s[threadIdx.x + off];
        __syncthreads();
    }
    if (threadIdx.x == 0) bs[blockIdx.x] = s[0];
}

__global__ void __launch_bounds__(1024)
scan_top(int* __restrict__ bs, int nblk, int* __restrict__ rowStartN) {
    __shared__ int s[1024];
    int t = threadIdx.x;
    int x = (t < nblk) ? bs[t] : 0;
    s[t] = x;
    __syncthreads();
    for (int off = 1; off < 1024; off <<= 1) {
        int y = (t >= off) ? s[t - off] : 0;
        __syncthreads();
        s[t] += y;
        __syncthreads();
    }
    if (t < nblk) bs[t] = s[t] - x;
    if (t == 1023) *rowStartN = s[1023];
}

__global__ void __launch_bounds__(256)
scan_final(int* __restrict__ cur, const int* __restrict__ bs,
           int* __restrict__ rowStart, int n) {
    __shared__ int s[256];
    int t = threadIdx.x;
    int i = blockIdx.x * 256 + t;
    int x = (i < n) ? cur[i] : 0;
    s[t] = x;
    __syncthreads();
    for (int off = 1; off < 256; off <<= 1) {
        int y = (t >= off) ? s[t - off] : 0;
        __syncthreads();
        s[t] += y;
        __syncthreads();
    }
    int excl = s[t] - x + bs[blockIdx.x];
    if (i < n) { rowStart[i] = excl; cur[i] = excl; }
}

__global__ void scatter_kernel(const int* __restrict__ erows,
                               const int* __restrict__ ecols,
                               const float* __restrict__ evals,
                               int* __restrict__ cur, int2* __restrict__ pairs,
                               int n_edges) {
    int i = blockIdx.x * blockDim.x + threadIdx.x;
    int stride = gridDim.x * blockDim.x;
    for (int e = i; e < n_edges; e += stride) {
        int pos = atomicAdd(&cur[erows[e]], 1);
        pairs[pos] = make_int2(ecols[e], __float_as_int(evals[e]));
    }
}

__global__ void __launch_bounds__(256)
fused_kernel(const float* __restrict__ feat, const int* __restrict__ rowStart,
             const int2* __restrict__ pairs, const float* __restrict__ W,
             float* __restrict__ out, int n_rows) {
    __shared__ float sW[D * D];
    __shared__ float srow[4][D];
    for (int i = threadIdx.x; i < D * D; i += 256) sW[i] = W[i];
    const int w = threadIdx.x >> 6, lane = threadIdx.x & 63;
    const int row = blockIdx.x * 4 + w;
    float acc = 0.0f;
    if (row < n_rows) {
        int s = rowStart[row], e = rowStart[row + 1], i = s;
        for (; i + 4 <= e; i += 4) {
            int2 p0 = pairs[i + 0], p1 = pairs[i + 1];
            int2 p2 = pairs[i + 2], p3 = pairs[i + 3];
            float f0 = feat[(size_t)p0.x * D + lane];
            float f1 = feat[(size_t)p1.x * D + lane];
            float f2 = feat[(size_t)p2.x * D + lane];
            float f3 = feat[(size_t)p3.x * D + lane];
            acc = fmaf(f0, __int_as_float(p0.y), acc);
            acc = fmaf(f1, __int_as_float(p1.y), acc);
            acc = fmaf(f2, __int_as_float(p2.y), acc);
            acc = fmaf(f3, __int_as_float(p3.y), acc);
        }
        for (; i < e; ++i) {
            int2 p = pairs[i];
            acc = fmaf(feat[(size_t)p.x * D + lane], __int_as_float(p.y), acc);
        }
    }
    srow[w][lane] = acc;
    __syncthreads();
    float o = 0.0f;
#pragma unroll
    for (int k = 0; k < D; ++k) o = fmaf(srow[w][k], sW[k * D + lane], o);
    if (row < n_rows) out[(size_t)row * D + lane] = fmaxf(o, 0.0f);
}

__global__ void agg_kernel(const float* __restrict__ feat,
                           const int* __restrict__ erows,
                           const int* __restrict__ ecols,
                           const float* __restrict__ evals,
                           float* __restrict__ agg, int n_edges) {
    int gid = blockIdx.x * blockDim.x + threadIdx.x;
    int group = gid >> 4, lane4 = gid & 15;
    int stride = (gridDim.x * blockDim.x) >> 4;
    for (int e = group; e < n_edges; e += stride) {
        int r = erows[e], c = ecols[e];
        float v = evals[e];
        const float4 f = *reinterpret_cast<const float4*>(feat + (size_t)c * D + lane4 * 4);
        float* dst = agg + (size_t)r * D + lane4 * 4;
        unsafeAtomicAdd(dst + 0, f.x * v);
        unsafeAtomicAdd(dst + 1, f.y * v);
        unsafeAtomicAdd(dst + 2, f.z * v);
        unsafeAtomicAdd(dst + 3, f.w * v);
    }
}

__global__ void __launch_bounds__(256)
proj_kernel(const float* __restrict__ agg, const float* __restrict__ W,
            float* __restrict__ out, int n_rows) {
    __shared__ float sW[D * D];
    __shared__ float srow[4][D];
    for (int i = threadIdx.x; i < D * D; i += 256) sW[i] = W[i];
    __syncthreads();
    const int rg = threadIdx.x >> 6, j = threadIdx.x & 63;
    for (int row0 = blockIdx.x * 4; row0 < n_rows; row0 += gridDim.x * 4) {
        int r = row0 + rg;
        float v = (r < n_rows) ? agg[(size_t)r * D + j] : 0.0f;
        srow[rg][j] = v;
        __syncthreads();
        float acc = 0.0f;
#pragma unroll
        for (int k = 0; k < D; ++k) acc = fmaf(srow[rg][k], sW[k * D + j], acc);
        if (r < n_rows) out[(size_t)r * D + j] = fmaxf(acc, 0.0f);
        __syncthreads();
    }
}

// ===========================================================================
extern "C" void kernel_launch(void* const* d_in, const int* in_sizes, int n_in,
                              void* d_out, int out_size, void* d_ws, size_t ws_size,
                              hipStream_t stream) {
    const float* feat  = (const float*)d_in[0];
    const int*   erows = (const int*)  d_in[1];
    const int*   ecols = (const int*)  d_in[2];
    const float* evals = (const float*)d_in[3];
    const float* W     = (const float*)d_in[4];
    float*       out   = (float*)d_out;

    const int n_edges = in_sizes[1];
    const int n_nodes = in_sizes[0] / D;

    auto align256 = [](size_t x) { return (x + 255) & ~(size_t)255; };

    // ---- slot-path layout (SLOTS=32) ----
    size_t off_cnt    = 0;
    size_t off_ovfCnt = align256((size_t)n_nodes * 4);
    size_t off_ovf    = align256(off_ovfCnt + 4);
    size_t off_G      = align256(off_ovf + (size_t)OVF_CAP * 16);
    size_t off_pairs  = align256(off_G + (size_t)n_nodes * D * 2);
    size_t need_bf16  = off_pairs + (size_t)n_nodes * 32 * 8;
    // f32 tier reuses layout without G
    size_t off_pairs2 = off_G;
    size_t need_f32   = off_pairs2 + (size_t)n_nodes * 32 * 8;

    const int rows_per_slice8 = (n_nodes + 7) / 8;

    if (ws_size >= need_bf16 || ws_size >= need_f32) {
        char* ws     = (char*)d_ws;
        int*  cnt    = (int*) (ws + off_cnt);
        int*  ovfCnt = (int*) (ws + off_ovfCnt);
        int4* ovf    = (int4*)(ws + off_ovf);

        hipMemsetAsync(cnt, 0, (size_t)n_nodes * 4, stream);
        hipMemsetAsync(ovfCnt, 0, 4, stream);

        if (ws_size >= need_bf16) {
            unsigned short* G = (unsigned short*)(ws + off_G);
            int2* pairs = (int2*)(ws + off_pairs);
            gw_kernel<<<2048, 256, 0, stream>>>(feat, W, G, n_nodes);
            scatter_slot_kernel<32, 8><<<4096, 256, 0, stream>>>(
                erows, ecols, evals, cnt, pairs, ovf, ovfCnt, n_edges, rows_per_slice8);
            fused_gather2<32><<<2048, 256, 0, stream>>>(
                G, cnt, pairs, ovfCnt, out, n_nodes);
            ovf_kernel_g<<<256, 256, 0, stream>>>(G, ovf, ovfCnt, out);
        } else {
            int2* pairs = (int2*)(ws + off_pairs2);
            scatter_slot_kernel<32, 8><<<4096, 256, 0, stream>>>(
                erows, ecols, evals, cnt, pairs, ovf, ovfCnt, n_edges, rows_per_slice8);
            fused_slot_f32<32><<<(n_nodes + 3) / 4, 256, 0, stream>>>(
                feat, cnt, pairs, W, ovfCnt, out, n_nodes);
            ovf_kernel_fw<<<256, 256, 0, stream>>>(feat, W, ovf, ovfCnt, out);
        }
        relu_fix_kernel<<<512, 256, 0, stream>>>(out, ovfCnt, n_nodes * D);
        return;
    }

    // ---- CSR fallback ----
    const int nblk = (n_nodes + 255) / 256;
    size_t off_rowStart = 0;
    size_t off_cur      = align256(off_rowStart + (size_t)(n_nodes + 1) * 4);
    size_t off_bs       = align256(off_cur + (size_t)n_nodes * 4);
    size_t off_p        = align256(off_bs + (size_t)nblk * 4);
    size_t ws_needed    = off_p + (size_t)n_edges * 8;

    if (ws_size >= ws_needed && nblk <= 1024) {
        char* ws = (char*)d_ws;
        int*  rowStart = (int*) (ws + off_rowStart);
        int*  cur      = (int*) (ws + off_cur);
        int*  bs       = (int*) (ws + off_bs);
        int2* pairs    = (int2*)(ws + off_p);

        hipMemsetAsync(cur, 0, (size_t)n_nodes * 4, stream);
        hist_kernel<<<2048, 256, 0, stream>>>(erows, cur, n_edges);
        scan_block_reduce<<<nblk, 256, 0, stream>>>(cur, bs, n_nodes);
        scan_top<<<1, 1024, 0, stream>>>(bs, nblk, rowStart + n_nodes);
        scan_final<<<nblk, 256, 0, stream>>>(cur, bs, rowStart, n_nodes);
        scatter_kernel<<<2048, 256, 0, stream>>>(erows, ecols, evals, cur, pairs, n_edges);
        fused_kernel<<<(n_nodes + 3) / 4, 256, 0, stream>>>(feat, rowStart, pairs, W, out, n_nodes);
    } else {
        hipMemsetAsync(out, 0, (size_t)n_nodes * D * 4, stream);
        agg_kernel<<<2048, 256, 0, stream>>>(feat, erows, ecols, evals, out, n_edges);
        proj_kernel<<<2048, 256, 0, stream>>>(out, W, out, n_nodes);
    }
}